// Round 1
// baseline (291.942 us; speedup 1.0000x reference)
//
#include <hip/hip_runtime.h>
#include <math.h>

#define BB 16
#define H 1024
#define W 1024
#define HW (H*W)
#define NTOT (BB*HW)
#define CAP 262144u

typedef unsigned long long u64;

// float32 of np.exp(-0.5*(n/1)^2), n=-2..2 (correctly-rounded decimal literals)
__device__ __constant__ float GW[5] = {
    0.13533528323661270f, 0.60653065971263342f, 1.0f,
    0.60653065971263342f, 0.13533528323661270f};

// NMS neighbor offsets per direction bucket
// 0:E 1:SE 2:S 3:SW 4:W 5:NW 6:N 7:NE
__device__ __constant__ int NBDY[8] = {0, 1, 1, 1, 0, -1, -1, -1};
__device__ __constant__ int NBDX[8] = {1, 1, 0, -1, -1, -1, 0, 1};

#define CSCALE ((float)(180.0 / 3.1415926))

// =====================================================================
// K1: fully fused gaussian(h)+gaussian(v)+sobel+mag+bucket+NMS.
// Tile 64x16 output px. LDS ~15 KB -> 8 blocks/CU (32 waves, wave cap).
// Layout (all overlays barrier-separated):
//   sA[24*80]  : img rows y0-4..y0+19, cols x0-8..x0+71 (col c <-> x0-8+c)
//                -> overlay sm rows y0-2..y0+17 stride 80 (col s <-> x0-6+s)
//                -> tail (floats 1600..) bucket nibbles + red scratch
//   sB[24*76]  : gh rows 24, col s <-> x0-6+s
//                -> overlay mag rows y0-1..y0+16 stride 76 (col cm <-> x0-4+cm)
// NMS is division-free (verified compare scheme). The rare magmax-
// dependent tie band (a in (bp, bp*1.0000005)) is conservatively
// EXCLUDED and appended to a fixup list resolved in k_post once M is
// known (exclusion-only guess => fixup only adds pixels).
// =====================================================================
__global__ __launch_bounds__(256, 8) void k_smooth_sobel_nms(
    const float* __restrict__ img, float* __restrict__ thin,
    float* __restrict__ partialA, float* __restrict__ partialB,
    unsigned int* __restrict__ cnt, uint4* __restrict__ list) {
#pragma clang fp contract(off)
    __shared__ float sA[24 * 80];
    __shared__ float sB[24 * 76];
    unsigned short* sBk = (unsigned short*)&sA[1600];  // 18*18 ushort = 648 B
    float* redS = &sA[1800];                           // 8 floats scratch

    const int tid = threadIdx.x;
    const int x0 = blockIdx.x * 64;
    const int y0 = blockIdx.y * 16;
    const int b = blockIdx.z;
    const size_t base = (size_t)b * HW;

    // ---- stage A: img tile + halo: 24 rows x 20 quads (cols x0-8..x0+71) ----
    for (int idx = tid; idx < 24 * 20; idx += 256) {
        int r = idx / 20, v = idx - r * 20;
        int gy = y0 - 4 + r;
        int gxv = x0 - 8 + v * 4;
        float4 val = make_float4(0.f, 0.f, 0.f, 0.f);
        if (gy >= 0 && gy < H && gxv >= 0 && gxv <= W - 4)
            val = *(const float4*)&img[base + (size_t)gy * W + gxv];
        *(float4*)&sA[r * 80 + v * 4] = val;
    }
    __syncthreads();

    // ---- stage B: horizontal gaussian, 24 rows x 19 quads (cols x0-6..x0+69) ----
    // gh[s] needs img cols s..s+4 of sA (offset-0 mapping -> only 2 quads)
    for (int idx = tid; idx < 24 * 19; idx += 256) {
        int r = idx / 19, g = idx - r * 19;
        const float* p = &sA[r * 80 + g * 4];
        float4 A0 = *(const float4*)p;
        float4 A1 = *(const float4*)(p + 4);
        float a_[8] = {A0.x, A0.y, A0.z, A0.w, A1.x, A1.y, A1.z, A1.w};
        float o[4];
#pragma unroll
        for (int j = 0; j < 4; ++j) {
            float s = 0.0f;
#pragma unroll
            for (int k = 0; k < 5; ++k) s = s + GW[k] * a_[j + k];
            o[j] = s;
        }
        *(float4*)&sB[r * 76 + g * 4] = make_float4(o[0], o[1], o[2], o[3]);
    }
    __syncthreads();

    // ---- stage C: vertical gaussian -> sm (overlays sA), ZERO at image OOB ----
    // sm rows rr <-> gy=y0-2+rr (20 rows), reads gh rows rr..rr+4
    for (int idx = tid; idx < 20 * 19; idx += 256) {
        int rr = idx / 19, g = idx - rr * 19;
        float bb[20];
#pragma unroll
        for (int k = 0; k < 5; ++k) {
            float4 t = *(const float4*)&sB[(rr + k) * 76 + g * 4];
            bb[k * 4 + 0] = t.x; bb[k * 4 + 1] = t.y;
            bb[k * 4 + 2] = t.z; bb[k * 4 + 3] = t.w;
        }
        int gy = y0 - 2 + rr;
        bool rowok = (gy >= 0 && gy < H);
        float o[4];
#pragma unroll
        for (int j = 0; j < 4; ++j) {
            float s = 0.0f;
#pragma unroll
            for (int k = 0; k < 5; ++k) s = s + GW[k] * bb[k * 4 + j];
            int gx = x0 - 6 + g * 4 + j;
            o[j] = (rowok && gx >= 0 && gx < W) ? s : 0.0f;
        }
        *(float4*)&sA[rr * 80 + g * 4] = make_float4(o[0], o[1], o[2], o[3]);
    }
    __syncthreads();

    // ---- stage D: sobel + mag + bucket over mag tile (18 rows x 72 cols,
    //      rows gy=y0-1+m, cols gx=x0-4+cm) -> mag overlays sB, buckets to sBk ----
    for (int idx = tid; idx < 18 * 18; idx += 256) {
        int m = idx / 18, gq = idx - m * 18;
        const float* P0 = &sA[m * 80 + gq * 4];   // sm rows m..m+2
        const float* P1 = P0 + 80;
        const float* P2 = P1 + 80;
        float4 q0 = *(const float4*)P0; float4 e0 = *(const float4*)(P0 + 4);
        float4 q1 = *(const float4*)P1; float4 e1 = *(const float4*)(P1 + 4);
        float4 q2 = *(const float4*)P2; float4 e2 = *(const float4*)(P2 + 4);
        float r0[8] = {q0.x, q0.y, q0.z, q0.w, e0.x, e0.y, e0.z, e0.w};
        float r1[8] = {q1.x, q1.y, q1.z, q1.w, e1.x, e1.y, e1.z, e1.w};
        float r2[8] = {q2.x, q2.y, q2.z, q2.w, e2.x, e2.y, e2.z, e2.w};
        int gy = y0 - 1 + m;
        unsigned int bk = 0;
        float mg[4];
#pragma unroll
        for (int j = 0; j < 4; ++j) {
            float a00 = r0[j + 1], a01 = r0[j + 2], a02 = r0[j + 3];
            float a10 = r1[j + 1],                  a12 = r1[j + 3];
            float a20 = r2[j + 1], a21 = r2[j + 2], a22 = r2[j + 3];

            float Ix = a00;
            Ix = Ix - a02;
            Ix = Ix + 2.0f * a10;
            Ix = Ix - 2.0f * a12;
            Ix = Ix + a20;
            Ix = Ix - a22;

            float Iy = a00;
            Iy = Iy + 2.0f * a01;
            Iy = Iy + a02;
            Iy = Iy - a20;
            Iy = Iy - 2.0f * a21;
            Iy = Iy - a22;

            float t1 = Ix * Ix;
            float t2 = Iy * Iy;
            float m2 = sqrtf(t1 + t2);
            int gx = x0 - 4 + gq * 4 + j;
            if (gy < 0 || gy >= H || gx < 0 || gx >= W) m2 = 0.0f;  // zero-pad like ref
            mg[j] = m2;

            // octant by comparisons; conservative band -> exact double fallback
            float ax = fabsf(Ix), ay = fabsf(Iy);
            float mn = fminf(ax, ay), mx = fmaxf(ax, ay);
            float cr = mn * 0.92387953f - mx * 0.38268343f;
            int bidx;
            if (fabsf(cr) < mx * 3e-5f) {
                float fa2 = (float)atan2((double)Iy, (double)Ix);
                float d2 = fa2 * CSCALE;
                d2 = d2 + 180.0f;
                float t2d = d2 / 45.0f;
                float rr2 = rintf(t2d);
                bidx = ((int)rr2) & 7;
            } else if (ay <= ax * 0.41421356f) {
                bidx = signbit(Ix) ? 0 : 4;
            } else if (ay >= ax * 2.41421356f) {
                bidx = (Iy >= 0.0f) ? 6 : 2;
            } else {
                bidx = (Iy >= 0.0f) ? ((Ix >= 0.0f) ? 5 : 7)
                                    : ((Ix >= 0.0f) ? 3 : 1);
            }
            bk |= ((unsigned int)bidx) << (4 * j);
        }
        *(float4*)&sB[m * 76 + gq * 4] = make_float4(mg[0], mg[1], mg[2], mg[3]);
        sBk[m * 18 + gq] = (unsigned short)bk;
    }
    __syncthreads();

    // ---- stage E: NMS (division-free) + thin write + block maxima ----
    const int r = tid >> 4;            // 0..15
    const int cg = (tid & 15) * 4;     // 0..60
    const int y = y0 + r;
    const int m = r + 1;
    float tmax = 0.0f, amax = 0.0f;
    {
        unsigned int bk4 = sBk[m * 18 + (cg >> 2) + 1];
        float4 a4 = *(const float4*)&sB[m * 76 + cg + 4];
        float av[4] = {a4.x, a4.y, a4.z, a4.w};
        float o[4];
#pragma unroll
        for (int j = 0; j < 4; ++j) {
            int bkt = (bk4 >> (4 * j)) & 7;
            int dy = NBDY[bkt], dx = NBDX[bkt];
            int cm = cg + 4 + j;
            float a = av[j];
            float bp = sB[(m + dy) * 76 + cm + dx];
            float bn = sB[(m - dy) * 76 + cm - dx];
            bool g1 = a > bp, g2 = a > bn;
            bool im = g1 && g2;
            if (im) {
                bool f1 = a >= bp * 1.0000005f;
                bool f2 = a >= bn * 1.0000005f;
                if (!(f1 && f2)) {
                    // uncertain tie band: conservatively exclude, log for fixup
                    im = false;
                    unsigned int id = atomicAdd(cnt, 1u);
                    if (id < CAP) {
                        uint4 e;
                        e.x = (unsigned int)(base + (size_t)y * W + x0 + cg + j);
                        e.y = __float_as_uint(a);
                        e.z = __float_as_uint(bp);
                        e.w = __float_as_uint(bn);
                        list[id] = e;
                    }
                }
            }
            tmax = fmaxf(tmax, a);          // raw magmax over ALL interior px
            if (im) amax = fmaxf(amax, a);  // thin max over confirmed px
            o[j] = im ? a : 0.0f;
        }
        *(float4*)&thin[base + (size_t)y * W + x0 + cg] =
            make_float4(o[0], o[1], o[2], o[3]);
    }
#pragma unroll
    for (int off = 32; off > 0; off >>= 1) {
        tmax = fmaxf(tmax, __shfl_down(tmax, off));
        amax = fmaxf(amax, __shfl_down(amax, off));
    }
    if ((tid & 63) == 0) { redS[tid >> 6] = tmax; redS[4 + (tid >> 6)] = amax; }
    __syncthreads();
    if (tid == 0) {
        float tA = fmaxf(fmaxf(redS[0], redS[1]), fmaxf(redS[2], redS[3]));
        float tB = fmaxf(fmaxf(redS[4], redS[5]), fmaxf(redS[6], redS[7]));
        int pb = (b * 64 + blockIdx.y) * 16 + blockIdx.x;  // 1024 per image
        partialA[pb] = tA;
        partialB[pb] = tB;
    }
}

// =====================================================================
// k_post (single block, 1024 thr): per-image magmax M -> fixup the
// uncertain-tie list (exact division path, adds-only) -> per-image thin
// max (partials + fixup adds) -> global thin max + threshold bisection.
// =====================================================================
__global__ __launch_bounds__(1024) void k_post(const float* __restrict__ partialA,
                                               const float* __restrict__ partialB,
                                               const unsigned int* __restrict__ cnt,
                                               const uint4* __restrict__ list,
                                               float* __restrict__ thin,
                                               float* __restrict__ hdr,
                                               float* __restrict__ thr) {
#pragma clang fp contract(off)
    __shared__ float sM[16];
    __shared__ int sAmaxI[16];   // float-as-int (>=0) thin-max additions
    __shared__ float sTm[16];
    __shared__ float sTmAll;
    const int tid = threadIdx.x;
    const int iw = tid >> 6, lane = tid & 63;   // wave iw owns image iw

    // phase A: per-image magmax
    {
        const float* p = partialA + iw * 1024;
        float m = 0.0f;
        for (int k = lane; k < 1024; k += 64) m = fmaxf(m, p[k]);
        for (int off = 32; off > 0; off >>= 1) m = fmaxf(m, __shfl_down(m, off));
        if (lane == 0) { sM[iw] = m; sAmaxI[iw] = 0; hdr[iw] = m; }
    }
    __syncthreads();

    // phase B: fixup uncertain NMS ties (only ADDS pixels)
    {
        unsigned int n = *cnt;
        if (n > CAP) n = CAP;
        for (unsigned int i = tid; i < n; i += 1024) {
            uint4 e = list[i];
            float a = __uint_as_float(e.y);
            float bp = __uint_as_float(e.z);
            float bn = __uint_as_float(e.w);
            int b = (int)(e.x >> 20);
            float M = sM[b];
            // appended only when g1&&g2 held; resolve strict > after /M exactly
            bool f1 = a >= bp * 1.0000005f;
            bool f2 = a >= bn * 1.0000005f;
            float qa = a / M;
            bool r1 = f1 ? true : (qa > (bp / M));
            bool r2 = f2 ? true : (qa > (bn / M));
            if (r1 && r2) {
                thin[e.x] = a;
                atomicMax(&sAmaxI[b], __float_as_int(a));
            }
        }
    }
    __syncthreads();

    // phase C: per-image thin max -> normalized (RN monotone => exact)
    {
        const float* p = partialB + iw * 1024;
        float m = 0.0f;
        for (int k = lane; k < 1024; k += 64) m = fmaxf(m, p[k]);
        for (int off = 32; off > 0; off >>= 1) m = fmaxf(m, __shfl_down(m, off));
        if (lane == 0) {
            m = fmaxf(m, __int_as_float(sAmaxI[iw]));
            sTm[iw] = m / sM[iw];
        }
    }
    __syncthreads();
    if (tid == 0) {
        float tm = 0.0f;
        for (int i = 0; i < 16; ++i) tm = fmaxf(tm, sTm[i]);
        hdr[16] = tm;
        sTmAll = tm;
    }
    __syncthreads();
    // threshold bisection: smallest float x with x/M >= T
    if (tid < 32) {
        float tm = sTmAll;
        int t = tid;
        float M = sM[t >> 1];
        float T = (t & 1) ? (tm * 0.15f) : 0.00392f;
        if (0.0f / M >= T) { thr[t] = 0.0f; return; }
        unsigned int lo = 0u, hi = 0x7f800000u;
        while (hi - lo > 1u) {
            unsigned int mid = lo + ((hi - lo) >> 1);
            if (__uint_as_float(mid) / M >= T) hi = mid; else lo = mid;
        }
        thr[t] = __uint_as_float(hi);
    }
}

// ---------------- threshold: thin -> Sb/Wb (no division, no Mb) ----------------
// thin>0 <=> is_max, and Alo/Ahi > 0 whenever snm is false, so the old
// im-gate is redundant: strong = snm || thin>=Ahi; weak = !strong && thin>=Alo.
__global__ __launch_bounds__(256, 8) void k_thresh_b(const float* __restrict__ thin,
                                                     const float* __restrict__ hdr,
                                                     const float* __restrict__ thr,
                                                     u64* __restrict__ Sb,
                                                     u64* __restrict__ Wb) {
    __shared__ unsigned int nibS[256], nibW[256];
    const int tid = threadIdx.x;
    const int x0 = blockIdx.x * 128;
    const int y0 = blockIdx.y * 32;
    const int b = blockIdx.z;
    const size_t base = (size_t)b * HW;
    const float Alo = thr[b * 2], Ahi = thr[b * 2 + 1];
    const bool snm = (hdr[16] * 0.15f <= 0.0f);
    const int r = tid >> 5;
    const int cg = (tid & 31) * 4;

    for (int k4 = 0; k4 < 4; ++k4) {
        const int rr = k4 * 8 + r;
        const int y = y0 + rr;
        float4 a4 = *(const float4*)&thin[base + (size_t)y * W + x0 + cg];
        float av[4] = {a4.x, a4.y, a4.z, a4.w};
        unsigned int ns = 0, nw = 0;
#pragma unroll
        for (int j = 0; j < 4; ++j) {
            bool strong = snm || (av[j] >= Ahi);
            bool weak = (!strong) && (av[j] >= Alo);
            ns |= (strong ? 1u : 0u) << j;
            nw |= (weak ? 1u : 0u) << j;
        }
        nibS[tid] = ns;
        nibW[tid] = nw;
        __syncthreads();
        if (tid < 32) {
            bool isW = (tid >= 16);
            int t = tid & 15;
            int rw = t >> 1, h = t & 1;
            const unsigned int* nb = isW ? nibW : nibS;
            u64 w = 0;
#pragma unroll
            for (int j = 0; j < 16; ++j)
                w |= (u64)nb[rw * 32 + h * 16 + j] << (4 * j);
            int yy = y0 + k4 * 8 + rw;
            int widx2 = ((b << 8) | ((yy >> 6) << 4) | ((x0 >> 6) + h)) * 64 + (yy & 63);
            if (isW) Wb[widx2] = w; else Sb[widx2] = w;
        }
        __syncthreads();
    }
}

// ---------------- hysteresis: bit-parallel 64x64 tile per wave, tile-major ----------------
// LAST pass writes the 255/0 float output via shfl row-transpose (coalesced).
template <bool LAST>
__global__ __launch_bounds__(256) void k_hyster_bits(const u64* __restrict__ Wb,
                                                     u64* __restrict__ Sb,
                                                     float* __restrict__ out) {
    const int lane = threadIdx.x & 63;
    const int t = blockIdx.x * 4 + (threadIdx.x >> 6);  // tile id = b*256+ty*16+tx
    const int ty = (t >> 4) & 15;
    const int tx = t & 15;
    const int idx = t * 64 + lane;

    u64 S = Sb[idx];
    const u64 Wk = Wb[idx];

    u64 hstat = 0;
    if (tx > 0)  hstat |= (Sb[(t - 1) * 64 + lane] >> 63) & 1ull;
    if (tx < 15) hstat |= (Sb[(t + 1) * 64 + lane] & 1ull) << 63;

    u64 halo = 0;
    if (lane == 0 && ty > 0) {
        const int ta = t - 16;
        u64 tc = Sb[ta * 64 + 63];
        u64 hh = (tc << 1) | tc | (tc >> 1);
        if (tx > 0)  hh |= (Sb[(ta - 1) * 64 + 63] >> 63) & 1ull;
        if (tx < 15) hh |= (Sb[(ta + 1) * 64 + 63] & 1ull) << 63;
        halo = hh;
    }
    if (lane == 63 && ty < 15) {
        const int tb = t + 16;
        u64 tc = Sb[tb * 64 + 0];
        u64 hh = (tc << 1) | tc | (tc >> 1);
        if (tx > 0)  hh |= (Sb[(tb - 1) * 64 + 0] >> 63) & 1ull;
        if (tx < 15) hh |= (Sb[(tb + 1) * 64 + 0] & 1ull) << 63;
        halo = hh;
    }

    for (int it = 0; it < 160; ++it) {
        u64 hh = (S << 1) | S | (S >> 1) | hstat;
        u64 up = __shfl_up(hh, 1, 64);
        if (lane == 0) up = halo;
        u64 dn = __shfl_down(hh, 1, 64);
        if (lane == 63) dn = halo;
        u64 dil = hh | up | dn;
        u64 nS = S | (Wk & dil);
        bool ch = (nS != S);
        S = nS;
        if (!__any(ch)) break;
    }

    if (!LAST) {
        Sb[idx] = S;
    } else {
        const int bimg = t >> 8;
        float* op = out + (size_t)bimg * HW + (size_t)(ty * 64) * W + tx * 64 + lane;
#pragma unroll 4
        for (int rr = 0; rr < 64; ++rr) {
            u64 wrow = __shfl(S, rr, 64);
            op[(size_t)rr * W] = ((wrow >> lane) & 1ull) ? 255.0f : 0.0f;
        }
    }
}

extern "C" void kernel_launch(void* const* d_in, const int* in_sizes, int n_in,
                              void* d_out, int out_size, void* d_ws, size_t ws_size,
                              hipStream_t stream) {
    (void)in_sizes; (void)n_in; (void)out_size; (void)ws_size;
    const float* img = (const float*)d_in[0];
    float* out = (float*)d_out;

    // workspace layout
    float* hdr = (float*)d_ws;                       // [0..15]=magmax, [16]=thinmax
    float* thr = hdr + 64;                           // 32 floats: per-image Alo/Ahi
    unsigned int* cnt = (unsigned int*)(hdr + 96);   // fixup-list counter
    float* partialA = hdr + 128;                     // 16384 floats (K1 raw magmax)
    float* partialB = partialA + 16384;              // 16384 floats (K1 raw thinmax)
    uint4* list = (uint4*)(partialB + 16384);        // CAP entries * 16 B = 4 MB
    float* thin = (float*)((char*)list + (size_t)CAP * 16);  // 64 MB
    u64* Sb = (u64*)(thin + (size_t)NTOT);           // strong bits, 2 MB
    u64* Wb = Sb + NTOT / 64;                        // weak bits, 2 MB

    hipMemsetAsync(cnt, 0, sizeof(unsigned int), stream);

    dim3 blk(256);
    k_smooth_sobel_nms<<<dim3(16, 64, BB), blk, 0, stream>>>(img, thin, partialA,
                                                             partialB, cnt, list);
    k_post<<<dim3(1), dim3(1024), 0, stream>>>(partialA, partialB, cnt, list,
                                               thin, hdr, thr);
    k_thresh_b<<<dim3(8, 32, BB), blk, 0, stream>>>(thin, hdr, thr, Sb, Wb);
    for (int p = 0; p < 5; ++p)
        k_hyster_bits<false><<<dim3(NTOT / (64 * 64) / 4), blk, 0, stream>>>(Wb, Sb, out);
    k_hyster_bits<true><<<dim3(NTOT / (64 * 64) / 4), blk, 0, stream>>>(Wb, Sb, out);
}

// Round 6
// 258.378 us; speedup vs baseline: 1.1299x; 1.1299x over previous
//
#include <hip/hip_runtime.h>
#include <math.h>

#define BB 16
#define H 1024
#define W 1024
#define HW (H*W)
#define NTOT (BB*HW)
#define CAP 262144u

typedef unsigned long long u64;

// float32 of np.exp(-0.5*(n/1)^2), n=-2..2 (correctly-rounded decimal literals)
__device__ __constant__ float GW[5] = {
    0.13533528323661270f, 0.60653065971263342f, 1.0f,
    0.60653065971263342f, 0.13533528323661270f};

// NMS neighbor offsets per direction bucket
// 0:E 1:SE 2:S 3:SW 4:W 5:NW 6:N 7:NE
__device__ __constant__ int NBDY[8] = {0, 1, 1, 1, 0, -1, -1, -1};
__device__ __constant__ int NBDX[8] = {1, 1, 0, -1, -1, -1, 0, 1};

#define CSCALE ((float)(180.0 / 3.1415926))

// =====================================================================
// K1: fully fused gaussian(h)+gaussian(v)+sobel+mag+bucket+NMS.
// Tile 64x16 output px. LDS ~15 KB.
// __launch_bounds__(256,6): 85-VGPR cap. (256,8) capped at 64 regs and
// SPILLED (r1 counters: WRITE_SIZE 346 MB vs 64 MB of algorithmic
// output = scratch writebacks; VGPR_Count 32). 6 blocks/CU = 24 waves
// is still ample TLP for a ~60%-VALU kernel.
// Layout (all overlays barrier-separated):
//   sA[24*80]  : img rows y0-4..y0+19, cols x0-8..x0+71 (col c <-> x0-8+c)
//                -> overlay sm rows y0-2..y0+17 stride 80 (col s <-> x0-6+s)
//                -> tail (floats 1600..) bucket nibbles + red scratch
//   sB[24*76]  : gh rows 24, col s <-> x0-6+s
//                -> overlay mag rows y0-1..y0+16 stride 76 (col cm <-> x0-4+cm)
// NMS is division-free (verified compare scheme). The rare magmax-
// dependent tie band (a in (bp, bp*1.0000005)) is conservatively
// EXCLUDED and appended to a fixup list resolved in k_post once M is
// known (exclusion-only guess => fixup only adds pixels).
// =====================================================================
__global__ __launch_bounds__(256, 6) void k_smooth_sobel_nms(
    const float* __restrict__ img, float* __restrict__ thin,
    float* __restrict__ partialA, float* __restrict__ partialB,
    unsigned int* __restrict__ cnt, uint4* __restrict__ list) {
#pragma clang fp contract(off)
    __shared__ float sA[24 * 80];
    __shared__ float sB[24 * 76];
    unsigned short* sBk = (unsigned short*)&sA[1600];  // 18*18 ushort = 648 B
    float* redS = &sA[1800];                           // 8 floats scratch

    const int tid = threadIdx.x;
    const int x0 = blockIdx.x * 64;
    const int y0 = blockIdx.y * 16;
    const int b = blockIdx.z;
    const size_t base = (size_t)b * HW;

    // ---- stage A: img tile + halo: 24 rows x 20 quads (cols x0-8..x0+71) ----
    for (int idx = tid; idx < 24 * 20; idx += 256) {
        int r = idx / 20, v = idx - r * 20;
        int gy = y0 - 4 + r;
        int gxv = x0 - 8 + v * 4;
        float4 val = make_float4(0.f, 0.f, 0.f, 0.f);
        if (gy >= 0 && gy < H && gxv >= 0 && gxv <= W - 4)
            val = *(const float4*)&img[base + (size_t)gy * W + gxv];
        *(float4*)&sA[r * 80 + v * 4] = val;
    }
    __syncthreads();

    // ---- stage B: horizontal gaussian, 24 rows x 19 quads (cols x0-6..x0+69) ----
    for (int idx = tid; idx < 24 * 19; idx += 256) {
        int r = idx / 19, g = idx - r * 19;
        const float* p = &sA[r * 80 + g * 4];
        float4 A0 = *(const float4*)p;
        float4 A1 = *(const float4*)(p + 4);
        float a_[8] = {A0.x, A0.y, A0.z, A0.w, A1.x, A1.y, A1.z, A1.w};
        float o[4];
#pragma unroll
        for (int j = 0; j < 4; ++j) {
            float s = 0.0f;
#pragma unroll
            for (int k = 0; k < 5; ++k) s = s + GW[k] * a_[j + k];
            o[j] = s;
        }
        *(float4*)&sB[r * 76 + g * 4] = make_float4(o[0], o[1], o[2], o[3]);
    }
    __syncthreads();

    // ---- stage C: vertical gaussian -> sm (overlays sA), ZERO at image OOB ----
    for (int idx = tid; idx < 20 * 19; idx += 256) {
        int rr = idx / 19, g = idx - rr * 19;
        float bb[20];
#pragma unroll
        for (int k = 0; k < 5; ++k) {
            float4 t = *(const float4*)&sB[(rr + k) * 76 + g * 4];
            bb[k * 4 + 0] = t.x; bb[k * 4 + 1] = t.y;
            bb[k * 4 + 2] = t.z; bb[k * 4 + 3] = t.w;
        }
        int gy = y0 - 2 + rr;
        bool rowok = (gy >= 0 && gy < H);
        float o[4];
#pragma unroll
        for (int j = 0; j < 4; ++j) {
            float s = 0.0f;
#pragma unroll
            for (int k = 0; k < 5; ++k) s = s + GW[k] * bb[k * 4 + j];
            int gx = x0 - 6 + g * 4 + j;
            o[j] = (rowok && gx >= 0 && gx < W) ? s : 0.0f;
        }
        *(float4*)&sA[rr * 80 + g * 4] = make_float4(o[0], o[1], o[2], o[3]);
    }
    __syncthreads();

    // ---- stage D: sobel + mag + bucket over mag tile (18 rows x 72 cols,
    //      rows gy=y0-1+m, cols gx=x0-4+cm) -> mag overlays sB, buckets to sBk ----
    for (int idx = tid; idx < 18 * 18; idx += 256) {
        int m = idx / 18, gq = idx - m * 18;
        const float* P0 = &sA[m * 80 + gq * 4];   // sm rows m..m+2
        const float* P1 = P0 + 80;
        const float* P2 = P1 + 80;
        float4 q0 = *(const float4*)P0; float4 e0 = *(const float4*)(P0 + 4);
        float4 q1 = *(const float4*)P1; float4 e1 = *(const float4*)(P1 + 4);
        float4 q2 = *(const float4*)P2; float4 e2 = *(const float4*)(P2 + 4);
        float r0[8] = {q0.x, q0.y, q0.z, q0.w, e0.x, e0.y, e0.z, e0.w};
        float r1[8] = {q1.x, q1.y, q1.z, q1.w, e1.x, e1.y, e1.z, e1.w};
        float r2[8] = {q2.x, q2.y, q2.z, q2.w, e2.x, e2.y, e2.z, e2.w};
        int gy = y0 - 1 + m;
        unsigned int bk = 0;
        float mg[4];
#pragma unroll
        for (int j = 0; j < 4; ++j) {
            float a00 = r0[j + 1], a01 = r0[j + 2], a02 = r0[j + 3];
            float a10 = r1[j + 1],                  a12 = r1[j + 3];
            float a20 = r2[j + 1], a21 = r2[j + 2], a22 = r2[j + 3];

            float Ix = a00;
            Ix = Ix - a02;
            Ix = Ix + 2.0f * a10;
            Ix = Ix - 2.0f * a12;
            Ix = Ix + a20;
            Ix = Ix - a22;

            float Iy = a00;
            Iy = Iy + 2.0f * a01;
            Iy = Iy + a02;
            Iy = Iy - a20;
            Iy = Iy - 2.0f * a21;
            Iy = Iy - a22;

            float t1 = Ix * Ix;
            float t2 = Iy * Iy;
            float m2 = sqrtf(t1 + t2);
            int gx = x0 - 4 + gq * 4 + j;
            if (gy < 0 || gy >= H || gx < 0 || gx >= W) m2 = 0.0f;  // zero-pad like ref
            mg[j] = m2;

            // octant by comparisons; conservative band -> exact double fallback
            float ax = fabsf(Ix), ay = fabsf(Iy);
            float mn = fminf(ax, ay), mx = fmaxf(ax, ay);
            float cr = mn * 0.92387953f - mx * 0.38268343f;
            int bidx;
            if (fabsf(cr) < mx * 3e-5f) {
                float fa2 = (float)atan2((double)Iy, (double)Ix);
                float d2 = fa2 * CSCALE;
                d2 = d2 + 180.0f;
                float t2d = d2 / 45.0f;
                float rr2 = rintf(t2d);
                bidx = ((int)rr2) & 7;
            } else if (ay <= ax * 0.41421356f) {
                bidx = signbit(Ix) ? 0 : 4;
            } else if (ay >= ax * 2.41421356f) {
                bidx = (Iy >= 0.0f) ? 6 : 2;
            } else {
                bidx = (Iy >= 0.0f) ? ((Ix >= 0.0f) ? 5 : 7)
                                    : ((Ix >= 0.0f) ? 3 : 1);
            }
            bk |= ((unsigned int)bidx) << (4 * j);
        }
        *(float4*)&sB[m * 76 + gq * 4] = make_float4(mg[0], mg[1], mg[2], mg[3]);
        sBk[m * 18 + gq] = (unsigned short)bk;
    }
    __syncthreads();

    // ---- stage E: NMS (division-free) + thin write + block maxima ----
    const int r = tid >> 4;            // 0..15
    const int cg = (tid & 15) * 4;     // 0..60
    const int y = y0 + r;
    const int m = r + 1;
    float tmax = 0.0f, amax = 0.0f;
    {
        unsigned int bk4 = sBk[m * 18 + (cg >> 2) + 1];
        float4 a4 = *(const float4*)&sB[m * 76 + cg + 4];
        float av[4] = {a4.x, a4.y, a4.z, a4.w};
        float o[4];
#pragma unroll
        for (int j = 0; j < 4; ++j) {
            int bkt = (bk4 >> (4 * j)) & 7;
            int dy = NBDY[bkt], dx = NBDX[bkt];
            int cm = cg + 4 + j;
            float a = av[j];
            float bp = sB[(m + dy) * 76 + cm + dx];
            float bn = sB[(m - dy) * 76 + cm - dx];
            bool g1 = a > bp, g2 = a > bn;
            bool im = g1 && g2;
            if (im) {
                bool f1 = a >= bp * 1.0000005f;
                bool f2 = a >= bn * 1.0000005f;
                if (!(f1 && f2)) {
                    // uncertain tie band: conservatively exclude, log for fixup
                    im = false;
                    unsigned int id = atomicAdd(cnt, 1u);
                    if (id < CAP) {
                        uint4 e;
                        e.x = (unsigned int)(base + (size_t)y * W + x0 + cg + j);
                        e.y = __float_as_uint(a);
                        e.z = __float_as_uint(bp);
                        e.w = __float_as_uint(bn);
                        list[id] = e;
                    }
                }
            }
            tmax = fmaxf(tmax, a);          // raw magmax over ALL interior px
            if (im) amax = fmaxf(amax, a);  // thin max over confirmed px
            o[j] = im ? a : 0.0f;
        }
        *(float4*)&thin[base + (size_t)y * W + x0 + cg] =
            make_float4(o[0], o[1], o[2], o[3]);
    }
#pragma unroll
    for (int off = 32; off > 0; off >>= 1) {
        tmax = fmaxf(tmax, __shfl_down(tmax, off));
        amax = fmaxf(amax, __shfl_down(amax, off));
    }
    if ((tid & 63) == 0) { redS[tid >> 6] = tmax; redS[4 + (tid >> 6)] = amax; }
    __syncthreads();
    if (tid == 0) {
        float tA = fmaxf(fmaxf(redS[0], redS[1]), fmaxf(redS[2], redS[3]));
        float tB = fmaxf(fmaxf(redS[4], redS[5]), fmaxf(redS[6], redS[7]));
        int pb = (b * 64 + blockIdx.y) * 16 + blockIdx.x;  // 1024 per image
        partialA[pb] = tA;
        partialB[pb] = tB;
    }
}

// =====================================================================
// k_post (single block, 1024 thr): per-image magmax M -> fixup the
// uncertain-tie list (exact division path, adds-only) -> per-image thin
// max (partials + fixup adds) -> global thin max + threshold bisection.
// =====================================================================
__global__ __launch_bounds__(1024) void k_post(const float* __restrict__ partialA,
                                               const float* __restrict__ partialB,
                                               const unsigned int* __restrict__ cnt,
                                               const uint4* __restrict__ list,
                                               float* __restrict__ thin,
                                               float* __restrict__ hdr,
                                               float* __restrict__ thr) {
#pragma clang fp contract(off)
    __shared__ float sM[16];
    __shared__ int sAmaxI[16];   // float-as-int (>=0) thin-max additions
    __shared__ float sTm[16];
    __shared__ float sTmAll;
    const int tid = threadIdx.x;
    const int iw = tid >> 6, lane = tid & 63;   // wave iw owns image iw

    // phase A: per-image magmax
    {
        const float* p = partialA + iw * 1024;
        float m = 0.0f;
        for (int k = lane; k < 1024; k += 64) m = fmaxf(m, p[k]);
        for (int off = 32; off > 0; off >>= 1) m = fmaxf(m, __shfl_down(m, off));
        if (lane == 0) { sM[iw] = m; sAmaxI[iw] = 0; hdr[iw] = m; }
    }
    __syncthreads();

    // phase B: fixup uncertain NMS ties (only ADDS pixels)
    {
        unsigned int n = *cnt;
        if (n > CAP) n = CAP;
        for (unsigned int i = tid; i < n; i += 1024) {
            uint4 e = list[i];
            float a = __uint_as_float(e.y);
            float bp = __uint_as_float(e.z);
            float bn = __uint_as_float(e.w);
            int b = (int)(e.x >> 20);
            float M = sM[b];
            // appended only when g1&&g2 held; resolve strict > after /M exactly
            bool f1 = a >= bp * 1.0000005f;
            bool f2 = a >= bn * 1.0000005f;
            float qa = a / M;
            bool r1 = f1 ? true : (qa > (bp / M));
            bool r2 = f2 ? true : (qa > (bn / M));
            if (r1 && r2) {
                thin[e.x] = a;
                atomicMax(&sAmaxI[b], __float_as_int(a));
            }
        }
    }
    __syncthreads();

    // phase C: per-image thin max -> normalized (RN monotone => exact)
    {
        const float* p = partialB + iw * 1024;
        float m = 0.0f;
        for (int k = lane; k < 1024; k += 64) m = fmaxf(m, p[k]);
        for (int off = 32; off > 0; off >>= 1) m = fmaxf(m, __shfl_down(m, off));
        if (lane == 0) {
            m = fmaxf(m, __int_as_float(sAmaxI[iw]));
            sTm[iw] = m / sM[iw];
        }
    }
    __syncthreads();
    if (tid == 0) {
        float tm = 0.0f;
        for (int i = 0; i < 16; ++i) tm = fmaxf(tm, sTm[i]);
        hdr[16] = tm;
        sTmAll = tm;
    }
    __syncthreads();
    // threshold bisection: smallest float x with x/M >= T
    if (tid < 32) {
        float tm = sTmAll;
        int t = tid;
        float M = sM[t >> 1];
        float T = (t & 1) ? (tm * 0.15f) : 0.00392f;
        if (0.0f / M >= T) { thr[t] = 0.0f; return; }
        unsigned int lo = 0u, hi = 0x7f800000u;
        while (hi - lo > 1u) {
            unsigned int mid = lo + ((hi - lo) >> 1);
            if (__uint_as_float(mid) / M >= T) hi = mid; else lo = mid;
        }
        thr[t] = __uint_as_float(hi);
    }
}

// ---------------- threshold: thin -> Sb/Wb (no division, no Mb) ----------------
// thin>0 <=> is_max, and Alo/Ahi > 0 whenever snm is false, so the old
// im-gate is redundant: strong = snm || thin>=Ahi; weak = !strong && thin>=Alo.
__global__ __launch_bounds__(256, 8) void k_thresh_b(const float* __restrict__ thin,
                                                     const float* __restrict__ hdr,
                                                     const float* __restrict__ thr,
                                                     u64* __restrict__ Sb,
                                                     u64* __restrict__ Wb) {
    __shared__ unsigned int nibS[256], nibW[256];
    const int tid = threadIdx.x;
    const int x0 = blockIdx.x * 128;
    const int y0 = blockIdx.y * 32;
    const int b = blockIdx.z;
    const size_t base = (size_t)b * HW;
    const float Alo = thr[b * 2], Ahi = thr[b * 2 + 1];
    const bool snm = (hdr[16] * 0.15f <= 0.0f);
    const int r = tid >> 5;
    const int cg = (tid & 31) * 4;

    for (int k4 = 0; k4 < 4; ++k4) {
        const int rr = k4 * 8 + r;
        const int y = y0 + rr;
        float4 a4 = *(const float4*)&thin[base + (size_t)y * W + x0 + cg];
        float av[4] = {a4.x, a4.y, a4.z, a4.w};
        unsigned int ns = 0, nw = 0;
#pragma unroll
        for (int j = 0; j < 4; ++j) {
            bool strong = snm || (av[j] >= Ahi);
            bool weak = (!strong) && (av[j] >= Alo);
            ns |= (strong ? 1u : 0u) << j;
            nw |= (weak ? 1u : 0u) << j;
        }
        nibS[tid] = ns;
        nibW[tid] = nw;
        __syncthreads();
        if (tid < 32) {
            bool isW = (tid >= 16);
            int t = tid & 15;
            int rw = t >> 1, h = t & 1;
            const unsigned int* nb = isW ? nibW : nibS;
            u64 w = 0;
#pragma unroll
            for (int j = 0; j < 16; ++j)
                w |= (u64)nb[rw * 32 + h * 16 + j] << (4 * j);
            int yy = y0 + k4 * 8 + rw;
            int widx2 = ((b << 8) | ((yy >> 6) << 4) | ((x0 >> 6) + h)) * 64 + (yy & 63);
            if (isW) Wb[widx2] = w; else Sb[widx2] = w;
        }
        __syncthreads();
    }
}

// ---------------- hysteresis: bit-parallel 64x64 tile per wave, tile-major ----------------
// LAST pass writes the 255/0 float output via shfl row-transpose (coalesced).
template <bool LAST>
__global__ __launch_bounds__(256) void k_hyster_bits(const u64* __restrict__ Wb,
                                                     u64* __restrict__ Sb,
                                                     float* __restrict__ out) {
    const int lane = threadIdx.x & 63;
    const int t = blockIdx.x * 4 + (threadIdx.x >> 6);  // tile id = b*256+ty*16+tx
    const int ty = (t >> 4) & 15;
    const int tx = t & 15;
    const int idx = t * 64 + lane;

    u64 S = Sb[idx];
    const u64 Wk = Wb[idx];

    u64 hstat = 0;
    if (tx > 0)  hstat |= (Sb[(t - 1) * 64 + lane] >> 63) & 1ull;
    if (tx < 15) hstat |= (Sb[(t + 1) * 64 + lane] & 1ull) << 63;

    u64 halo = 0;
    if (lane == 0 && ty > 0) {
        const int ta = t - 16;
        u64 tc = Sb[ta * 64 + 63];
        u64 hh = (tc << 1) | tc | (tc >> 1);
        if (tx > 0)  hh |= (Sb[(ta - 1) * 64 + 63] >> 63) & 1ull;
        if (tx < 15) hh |= (Sb[(ta + 1) * 64 + 63] & 1ull) << 63;
        halo = hh;
    }
    if (lane == 63 && ty < 15) {
        const int tb = t + 16;
        u64 tc = Sb[tb * 64 + 0];
        u64 hh = (tc << 1) | tc | (tc >> 1);
        if (tx > 0)  hh |= (Sb[(tb - 1) * 64 + 0] >> 63) & 1ull;
        if (tx < 15) hh |= (Sb[(tb + 1) * 64 + 0] & 1ull) << 63;
        halo = hh;
    }

    for (int it = 0; it < 160; ++it) {
        u64 hh = (S << 1) | S | (S >> 1) | hstat;
        u64 up = __shfl_up(hh, 1, 64);
        if (lane == 0) up = halo;
        u64 dn = __shfl_down(hh, 1, 64);
        if (lane == 63) dn = halo;
        u64 dil = hh | up | dn;
        u64 nS = S | (Wk & dil);
        bool ch = (nS != S);
        S = nS;
        if (!__any(ch)) break;
    }

    if (!LAST) {
        Sb[idx] = S;
    } else {
        const int bimg = t >> 8;
        float* op = out + (size_t)bimg * HW + (size_t)(ty * 64) * W + tx * 64 + lane;
#pragma unroll 4
        for (int rr = 0; rr < 64; ++rr) {
            u64 wrow = __shfl(S, rr, 64);
            op[(size_t)rr * W] = ((wrow >> lane) & 1ull) ? 255.0f : 0.0f;
        }
    }
}

extern "C" void kernel_launch(void* const* d_in, const int* in_sizes, int n_in,
                              void* d_out, int out_size, void* d_ws, size_t ws_size,
                              hipStream_t stream) {
    (void)in_sizes; (void)n_in; (void)out_size; (void)ws_size;
    const float* img = (const float*)d_in[0];
    float* out = (float*)d_out;

    // workspace layout
    float* hdr = (float*)d_ws;                       // [0..15]=magmax, [16]=thinmax
    float* thr = hdr + 64;                           // 32 floats: per-image Alo/Ahi
    unsigned int* cnt = (unsigned int*)(hdr + 96);   // fixup-list counter
    float* partialA = hdr + 128;                     // 16384 floats (K1 raw magmax)
    float* partialB = partialA + 16384;              // 16384 floats (K1 raw thinmax)
    uint4* list = (uint4*)(partialB + 16384);        // CAP entries * 16 B = 4 MB
    float* thin = (float*)((char*)list + (size_t)CAP * 16);  // 64 MB
    u64* Sb = (u64*)(thin + (size_t)NTOT);           // strong bits, 2 MB
    u64* Wb = Sb + NTOT / 64;                        // weak bits, 2 MB

    hipMemsetAsync(cnt, 0, sizeof(unsigned int), stream);

    dim3 blk(256);
    k_smooth_sobel_nms<<<dim3(16, 64, BB), blk, 0, stream>>>(img, thin, partialA,
                                                             partialB, cnt, list);
    k_post<<<dim3(1), dim3(1024), 0, stream>>>(partialA, partialB, cnt, list,
                                               thin, hdr, thr);
    k_thresh_b<<<dim3(8, 32, BB), blk, 0, stream>>>(thin, hdr, thr, Sb, Wb);
    for (int p = 0; p < 5; ++p)
        k_hyster_bits<false><<<dim3(NTOT / (64 * 64) / 4), blk, 0, stream>>>(Wb, Sb, out);
    k_hyster_bits<true><<<dim3(NTOT / (64 * 64) / 4), blk, 0, stream>>>(Wb, Sb, out);
}